// Round 1
// baseline (174.819 us; speedup 1.0000x reference)
//
#include <hip/hip_runtime.h>
#include <math.h>

// ============================================================================
// Sizes (fixed): N=2, C=64, Hax=56, W=56 -> B=112, H=56, OUT=64, N_HASHES=4,
// CHUNK=25, GROUPS=8, GP=8, hash_buckets=2, padding=19, K=3, qkv ch=96.
// Inputs fp32; OUTPUT FP32; stable argsort (established R8-R11).
// R15: (a) k3 fused single-pass: |ss|<=sqrt(2) (unit-16-vector pair sum) so
//      NO max pass; DI norm via 3x shfl_xor over g-lanes -> DI/WbK/update
//      phases + 3 barriers removed; LDS 39.9->28.8KB => 5 blocks/CU; static
//      (ks,jj) unroll => rel via s_loads. (b) k45 D-pass was 128 rolled
//      dependent global loads at 1 wave/SIMD => unroll 16; D stores
//      reciprocal; scatter unroll 4. (c) k12 o-quad GEMM tile (xv reuse 4x),
//      staging/sort unrolls.
//
// ws layout (float slots):
//   qkv : [112][5376]   off 0
//   bsb : [112][2400]   off 602112
//   Rb  : [112][38400]  off 870912
//   idx : [112][224]    off 5171712  (int)
// ============================================================================

#define EPSN 5e-5f
#define INV_EPSN 20000.0f
#define LOG2E 1.4426950408889634f
#define LN2   0.6931471805599453f

__device__ __forceinline__ float dot4(const float4 a, const float4 b) {
    return a.x * b.x + a.y * b.y + a.z * b.z + a.w * b.w;
}
__device__ __forceinline__ void fma4(float4& a, float s, const float4 v) {
    a.x += s * v.x; a.y += s * v.y; a.z += s * v.z; a.w += s * v.w;
}

// ---------------- K12: qkv GEMM + BN + LSH codes + stable argsort ----------------
// o-quad register tile (4 outputs share one xv read); float4 LDS reads.
__global__ __launch_bounds__(256) void k12_qkv_sort(
        const float* __restrict__ x, const float* __restrict__ cw,
        const float* __restrict__ gamma, const float* __restrict__ beta,
        const float* __restrict__ rot, float* __restrict__ qkv,
        int* __restrict__ idx_buf) {
    __shared__ float xsT[56 * 68];   // [h][c], pad 64->68 (16B-aligned rows)
    __shared__ float cws[96 * 64];
    __shared__ float wm[56 * 32];    // w_match[t][f]
    __shared__ float rl[128];
    __shared__ float gs[96], bt[96];
    __shared__ int code[224];
    __shared__ int srt[224];
    const int b = blockIdx.x, n = b / 56, w = b % 56, tid = threadIdx.x;
    const float* xb = x + n * 200704 + w;
    #pragma unroll 7
    for (int i = tid; i < 3584; i += 256) {
        int c = i / 56, h = i % 56;
        xsT[h * 68 + c] = xb[c * 3136 + h * 56];
    }
    #pragma unroll 8
    for (int i = tid; i < 6144; i += 256) cws[i] = cw[i];
    if (tid < 128) rl[tid] = rot[tid];
    if (tid < 96) { gs[tid] = gamma[tid]; bt[tid] = beta[tid]; }
    __syncthreads();
    const float inv_s = 1.0f / sqrtf(1.0f + 1.0e-5f);
    // 1344 tiles = 24 o-quads x 56 h; each tile: 4 outputs, xv read once.
    for (int tl = tid; tl < 1344; tl += 256) {
        int oq = tl / 56, h = tl % 56;
        int o0 = oq * 4;
        float s0 = 0.f, s1 = 0.f, s2 = 0.f, s3 = 0.f;
        #pragma unroll
        for (int cs = 0; cs < 16; ++cs) {
            float4 xv = *(const float4*)&xsT[h * 68 + cs * 4];
            float4 c0 = *(const float4*)&cws[(o0 + 0) * 64 + cs * 4];
            float4 c1 = *(const float4*)&cws[(o0 + 1) * 64 + cs * 4];
            float4 c2 = *(const float4*)&cws[(o0 + 2) * 64 + cs * 4];
            float4 c3 = *(const float4*)&cws[(o0 + 3) * 64 + cs * 4];
            s0 += dot4(xv, c0); s1 += dot4(xv, c1);
            s2 += dot4(xv, c2); s3 += dot4(xv, c3);
        }
        #pragma unroll
        for (int qq = 0; qq < 4; ++qq) {
            int o = o0 + qq;
            float sv = (qq == 0) ? s0 : (qq == 1) ? s1 : (qq == 2) ? s2 : s3;
            float val = sv * inv_s * gs[o] + bt[o];
            int j = o * 56 + h;
            qkv[b * 5376 + j] = val;
            int f = j % 96;                      // raw (B,96,56)->(B,56,96) reshape
            if (f < 32) wm[(j / 96) * 32 + f] = val;
        }
    }
    __syncthreads();
    if (tid < 224) {
        int u = tid / 56, t = tid % 56;
        float s = 0.f;
        #pragma unroll 8
        for (int f = 0; f < 32; ++f) s += wm[t * 32 + f] * rl[f * 4 + u];
        code[tid] = ((s < 0.f) ? 1 : 0) + 2 * u; // argmax([s,-s]) + u*hash_buckets
    }
    __syncthreads();
    if (tid < 224) {
        int c = code[tid], r = 0;
        #pragma unroll 8
        for (int p = 0; p < 224; ++p) {
            int cp = code[p];
            r += (int)((cp < c) | ((cp == c) & (p < tid)));  // stable rank
        }
        srt[r] = tid;
    }
    __syncthreads();
    if (tid < 224) idx_buf[b * 224 + tid] = srt[tid];
}

// ---------------- K3: chunked attention, one block per (b,u,k) ----------------
// Fused single-pass: l2-group-norm via shfl_xor over g (lanes&7), no max pass
// (|ss| <= sqrt(2) guaranteed by construction). LDS 28.8KB -> 5 blocks/CU.
__global__ __launch_bounds__(256, 5) void k3_attn(
        const float* __restrict__ qkv, const int* __restrict__ idx_buf,
        const float* __restrict__ rel, float* __restrict__ Rb,
        float* __restrict__ bsb) {
    __shared__ __align__(16) float Wc[8][3][25][4];   // l2-normalized w_b
    __shared__ __align__(16) float Vb[8][3][25][8];
    const int b = blockIdx.x, u = blockIdx.y, k = blockIdx.z;
    const int tid = threadIdx.x;
    const float* q = qkv + b * 5376;
    const int* ib = idx_buf + b * 224;

    #pragma unroll 3
    for (int idx = tid; idx < 600; idx += 256) {
        int i = idx % 25, kk = (idx / 25) % 3, g = idx / 75;
        int p0 = 1200 * g + 300 * u + 100 * kk + 4 * i;
        int h = p0 / 2400, r = p0 % 2400, t = r >> 5, f = r & 31;
        int row = (t < 56) ? t : t - 19;
        int tt = ib[h * 56 + row] % 56;
        float4 v = *(const float4*)&q[tt * 96 + f];
        float ni = fminf(__builtin_amdgcn_rsqf(dot4(v, v)), INV_EPSN);
        v.x *= ni; v.y *= ni; v.z *= ni; v.w *= ni;
        *(float4*)&Wc[g][kk][i][0] = v;
    }
    #pragma unroll 5
    for (int idx = tid; idx < 1200; idx += 256) {
        int half = idx & 1, fr = idx >> 1;
        int i = fr % 25, kk = (fr / 25) % 3, g = fr / 75;
        int p0 = 2400 * g + 600 * u + 200 * kk + 8 * i + 4 * half;
        int h = p0 / 4800, r = p0 % 4800, t = r >> 6, f = r & 63;
        int row = (t < 56) ? t : t - 19;
        int tt = ib[h * 56 + row] % 56;
        *(float4*)&Vb[g][kk][i][4 * half] = *(const float4*)&q[tt * 96 + 32 + f];
    }
    // wbr: raw (unnormalized) w_b at kk==k for this thread's (g,i) -- direct gather
    const int g = tid & 7, i = tid >> 3;
    float4 wbr = {0.f, 0.f, 0.f, 0.f};
    if (tid < 200) {
        int p0 = 1200 * g + 300 * u + 100 * k + 4 * i;
        int h = p0 / 2400, r = p0 % 2400, t = r >> 5, f = r & 31;
        int row = (t < 56) ? t : t - 19;
        int tt = ib[h * 56 + row] % 56;
        wbr = *(const float4*)&q[tt * 96 + f];
    }
    __syncthreads();
    if (tid < 200) {
        float se = 0.f;
        float4 a0 = {0,0,0,0}, a1 = {0,0,0,0}, a2 = {0,0,0,0}, a3 = {0,0,0,0};
        #pragma unroll
        for (int ks = 0; ks < 3; ++ks) {
            #pragma unroll
            for (int jj = 0; jj < 25; ++jj) {
                const int tw = ks * 25 + jj;                  // static
                const int roww = (tw < 56) ? tw : tw - 19;    // static -> s_loads
                float4 we = *(const float4*)&rel[roww * 12];
                float rawv = dot4(wbr, *(const float4*)&Wc[g][ks][jj][0]);
                float embv = 0.1f * dot4(wbr, we);            // F_GW folded
                float p2 = rawv * rawv + embv * embv;
                p2 += __shfl_xor(p2, 1);                      // sum over 8 g-lanes
                p2 += __shfl_xor(p2, 2);
                p2 += __shfl_xor(p2, 4);
                float di = fminf(__builtin_amdgcn_rsqf(p2), INV_EPSN);
                float e = __builtin_amdgcn_exp2f((rawv + embv) * di * LOG2E);
                se += e;
                const float4* vv = (const float4*)&Vb[g][ks][jj][0];
                fma4(a0, e, vv[0]); fma4(a1, e, vv[1]);
                float4 ve0 = *(const float4*)&rel[roww * 12 + 4];
                float4 ve1 = *(const float4*)&rel[roww * 12 + 8];
                fma4(a2, e, ve0); fma4(a3, e, ve1);
            }
        }
        bsb[b * 2400 + g * 300 + u * 75 + k * 25 + i] =
            __builtin_amdgcn_logf(se) * LN2;                  // logsumexp, no shift
        const float rinv = 1.0f / se;
        const float r2 = 0.1f * rinv;            // F_GV1
        a0.x *= rinv; a0.y *= rinv; a0.z *= rinv; a0.w *= rinv;
        a1.x *= rinv; a1.y *= rinv; a1.z *= rinv; a1.w *= rinv;
        a2.x *= r2;   a2.y *= r2;   a2.z *= r2;   a2.w *= r2;
        a3.x *= r2;   a3.y *= r2;   a3.z *= r2;   a3.w *= r2;
        float* rp = Rb + b * 38400 + 4800 * g + 1200 * u + 400 * k + 16 * i;
        ((float4*)rp)[0] = a0;
        ((float4*)rp)[1] = a1;
        ((float4*)rp)[2] = a2;
        ((float4*)rp)[3] = a3;
    }
}

// ---------------- K45: channel l2norm + pair-sum + unsort + hash softmax
//                        + transposed FP32 store ----------------
__global__ __launch_bounds__(256) void k45_post(
        const float* __restrict__ Rb, const float* __restrict__ bsb,
        const int* __restrict__ idx_buf, float* __restrict__ out) {
    __shared__ float D[300];
    __shared__ float bsn[300];
    __shared__ float retU[224][64];
    __shared__ float bsU[224];
    __shared__ int idxL[224];
    const int b = blockIdx.x, tid = threadIdx.x;
    const int n = b / 56, w = b % 56;
    const float* R = Rb + b * 38400;
    if (tid < 224) idxL[tid] = idx_buf[b * 224 + tid];
    for (int r = tid; r < 300; r += 256) {
        float s = 0.f;
        #pragma unroll 16                        // 16 loads in flight (1 wave/SIMD!)
        for (int c = 0; c < 128; ++c) { float v = R[c * 300 + r]; s += v * v; }
        D[r] = fminf(__builtin_amdgcn_rsqf(s), INV_EPSN);   // reciprocal norm
    }
    for (int idx = tid; idx < 300; idx += 256) {
        int u = idx / 75, t = idx % 75;
        float s2 = 0.f, sum = 0.f;
        #pragma unroll
        for (int g = 0; g < 8; ++g) {
            float v = bsb[b * 2400 + g * 300 + u * 75 + t];
            s2 += v * v; sum += v;
        }
        bsn[idx] = sum / fmaxf(sqrtf(s2), EPSN);
    }
    __syncthreads();
    #pragma unroll 4
    for (int idx = tid; idx < 224 * 64; idx += 256) {
        int p = idx >> 6, o = idx & 63;
        int u3 = p / 56, t = p % 56;
        int k3 = t / 25, i3 = t % 25;
        int q0 = 9600 * u3 + 3200 * k3 + 128 * i3 + 2 * o;
        float2 rv = *(const float2*)&R[q0];
        int r0 = q0 % 300;                       // q0 even => r0+1 never wraps
        float val = rv.x * D[r0] + rv.y * D[r0 + 1];
        int r = idxL[p];
        retU[r][o] = val;
        if (o == 0) bsU[r] = bsn[u3 * 75 + t];
    }
    __syncthreads();
    for (int idx = tid; idx < 56 * 64; idx += 256) {
        int h = idx >> 6, o = idx & 63;
        float b0 = bsU[h], b1 = bsU[56 + h], b2 = bsU[112 + h], b3 = bsU[168 + h];
        float m = fmaxf(fmaxf(b0, b1), fmaxf(b2, b3));
        float e0 = __builtin_amdgcn_exp2f((b0 - m) * LOG2E);
        float e1 = __builtin_amdgcn_exp2f((b1 - m) * LOG2E);
        float e2 = __builtin_amdgcn_exp2f((b2 - m) * LOG2E);
        float e3 = __builtin_amdgcn_exp2f((b3 - m) * LOG2E);
        float ps = e0 + e1 + e2 + e3;
        float val = (retU[h][o] * e0 + retU[56 + h][o] * e1 +
                     retU[112 + h][o] * e2 + retU[168 + h][o] * e3) / ps;
        out[((n * 64 + o) * 56 + h) * 56 + w] = val;   // (n,o,h,w)
    }
}

extern "C" void kernel_launch(void* const* d_in, const int* in_sizes, int n_in,
                              void* d_out, int out_size, void* d_ws, size_t ws_size,
                              hipStream_t stream) {
    (void)in_sizes; (void)n_in; (void)out_size; (void)ws_size;
    const float* x     = (const float*)d_in[0];
    const float* cw    = (const float*)d_in[1];
    const float* gamma = (const float*)d_in[2];
    const float* beta  = (const float*)d_in[3];
    const float* rel   = (const float*)d_in[4];
    const float* rot   = (const float*)d_in[5];
    float* ws  = (float*)d_ws;
    float* qkv = ws;
    float* bsb = ws + 602112;
    float* Rb  = ws + 870912;
    int*   idx = (int*)(ws + 5171712);

    k12_qkv_sort<<<112, 256, 0, stream>>>(x, cw, gamma, beta, rot, qkv, idx);
    k3_attn<<<dim3(112, 4, 3), 256, 0, stream>>>(qkv, idx, rel, Rb, bsb);
    k45_post<<<112, 256, 0, stream>>>(Rb, bsb, idx, (float*)d_out);
}

// Round 2
// 174.139 us; speedup vs baseline: 1.0039x; 1.0039x over previous
//
#include <hip/hip_runtime.h>
#include <math.h>

// ============================================================================
// Sizes (fixed): N=2, C=64, Hax=56, W=56 -> B=112, H=56, OUT=64, N_HASHES=4,
// CHUNK=25, GROUPS=8, GP=8, hash_buckets=2, padding=19, K=3, qkv ch=96.
// Inputs fp32; OUTPUT FP32; stable argsort (established R8-R11).
// R15: k3 fused single-pass (no max pass, |ss|<=sqrt(2)), shfl_xor group
//      norm, LDS 28.8KB, bank conflicts -> 0. BUT __launch_bounds__(256,5)
//      capped VGPR at 48 -> accumulator SPILL -> +46MB scratch HBM traffic
//      (FETCH 1.4->17.6MB, WRITE 18->47.7MB), k3 50->68us.
// R16: single-variable fix: drop the min-waves clamp (launch_bounds(256)).
//      LDS already allows 5 blocks/CU; let allocator use ~80-110 VGPRs,
//      no spill. k12/k45 unchanged (R15 versions helped ~13us).
//
// ws layout (float slots):
//   qkv : [112][5376]   off 0
//   bsb : [112][2400]   off 602112
//   Rb  : [112][38400]  off 870912
//   idx : [112][224]    off 5171712  (int)
// ============================================================================

#define EPSN 5e-5f
#define INV_EPSN 20000.0f
#define LOG2E 1.4426950408889634f
#define LN2   0.6931471805599453f

__device__ __forceinline__ float dot4(const float4 a, const float4 b) {
    return a.x * b.x + a.y * b.y + a.z * b.z + a.w * b.w;
}
__device__ __forceinline__ void fma4(float4& a, float s, const float4 v) {
    a.x += s * v.x; a.y += s * v.y; a.z += s * v.z; a.w += s * v.w;
}

// ---------------- K12: qkv GEMM + BN + LSH codes + stable argsort ----------------
// o-quad register tile (4 outputs share one xv read); float4 LDS reads.
__global__ __launch_bounds__(256) void k12_qkv_sort(
        const float* __restrict__ x, const float* __restrict__ cw,
        const float* __restrict__ gamma, const float* __restrict__ beta,
        const float* __restrict__ rot, float* __restrict__ qkv,
        int* __restrict__ idx_buf) {
    __shared__ float xsT[56 * 68];   // [h][c], pad 64->68 (16B-aligned rows)
    __shared__ float cws[96 * 64];
    __shared__ float wm[56 * 32];    // w_match[t][f]
    __shared__ float rl[128];
    __shared__ float gs[96], bt[96];
    __shared__ int code[224];
    __shared__ int srt[224];
    const int b = blockIdx.x, n = b / 56, w = b % 56, tid = threadIdx.x;
    const float* xb = x + n * 200704 + w;
    #pragma unroll 7
    for (int i = tid; i < 3584; i += 256) {
        int c = i / 56, h = i % 56;
        xsT[h * 68 + c] = xb[c * 3136 + h * 56];
    }
    #pragma unroll 8
    for (int i = tid; i < 6144; i += 256) cws[i] = cw[i];
    if (tid < 128) rl[tid] = rot[tid];
    if (tid < 96) { gs[tid] = gamma[tid]; bt[tid] = beta[tid]; }
    __syncthreads();
    const float inv_s = 1.0f / sqrtf(1.0f + 1.0e-5f);
    // 1344 tiles = 24 o-quads x 56 h; each tile: 4 outputs, xv read once.
    for (int tl = tid; tl < 1344; tl += 256) {
        int oq = tl / 56, h = tl % 56;
        int o0 = oq * 4;
        float s0 = 0.f, s1 = 0.f, s2 = 0.f, s3 = 0.f;
        #pragma unroll
        for (int cs = 0; cs < 16; ++cs) {
            float4 xv = *(const float4*)&xsT[h * 68 + cs * 4];
            float4 c0 = *(const float4*)&cws[(o0 + 0) * 64 + cs * 4];
            float4 c1 = *(const float4*)&cws[(o0 + 1) * 64 + cs * 4];
            float4 c2 = *(const float4*)&cws[(o0 + 2) * 64 + cs * 4];
            float4 c3 = *(const float4*)&cws[(o0 + 3) * 64 + cs * 4];
            s0 += dot4(xv, c0); s1 += dot4(xv, c1);
            s2 += dot4(xv, c2); s3 += dot4(xv, c3);
        }
        #pragma unroll
        for (int qq = 0; qq < 4; ++qq) {
            int o = o0 + qq;
            float sv = (qq == 0) ? s0 : (qq == 1) ? s1 : (qq == 2) ? s2 : s3;
            float val = sv * inv_s * gs[o] + bt[o];
            int j = o * 56 + h;
            qkv[b * 5376 + j] = val;
            int f = j % 96;                      // raw (B,96,56)->(B,56,96) reshape
            if (f < 32) wm[(j / 96) * 32 + f] = val;
        }
    }
    __syncthreads();
    if (tid < 224) {
        int u = tid / 56, t = tid % 56;
        float s = 0.f;
        #pragma unroll 8
        for (int f = 0; f < 32; ++f) s += wm[t * 32 + f] * rl[f * 4 + u];
        code[tid] = ((s < 0.f) ? 1 : 0) + 2 * u; // argmax([s,-s]) + u*hash_buckets
    }
    __syncthreads();
    if (tid < 224) {
        int c = code[tid], r = 0;
        #pragma unroll 8
        for (int p = 0; p < 224; ++p) {
            int cp = code[p];
            r += (int)((cp < c) | ((cp == c) & (p < tid)));  // stable rank
        }
        srt[r] = tid;
    }
    __syncthreads();
    if (tid < 224) idx_buf[b * 224 + tid] = srt[tid];
}

// ---------------- K3: chunked attention, one block per (b,u,k) ----------------
// Fused single-pass: l2-group-norm via shfl_xor over g (lanes&7), no max pass
// (|ss| <= sqrt(2) guaranteed by construction). LDS 28.8KB.
// NOTE: no min-waves clamp -- R15's (256,5) forced VGPR<=48 and spilled.
__global__ __launch_bounds__(256) void k3_attn(
        const float* __restrict__ qkv, const int* __restrict__ idx_buf,
        const float* __restrict__ rel, float* __restrict__ Rb,
        float* __restrict__ bsb) {
    __shared__ __align__(16) float Wc[8][3][25][4];   // l2-normalized w_b
    __shared__ __align__(16) float Vb[8][3][25][8];
    const int b = blockIdx.x, u = blockIdx.y, k = blockIdx.z;
    const int tid = threadIdx.x;
    const float* q = qkv + b * 5376;
    const int* ib = idx_buf + b * 224;

    #pragma unroll 3
    for (int idx = tid; idx < 600; idx += 256) {
        int i = idx % 25, kk = (idx / 25) % 3, g = idx / 75;
        int p0 = 1200 * g + 300 * u + 100 * kk + 4 * i;
        int h = p0 / 2400, r = p0 % 2400, t = r >> 5, f = r & 31;
        int row = (t < 56) ? t : t - 19;
        int tt = ib[h * 56 + row] % 56;
        float4 v = *(const float4*)&q[tt * 96 + f];
        float ni = fminf(__builtin_amdgcn_rsqf(dot4(v, v)), INV_EPSN);
        v.x *= ni; v.y *= ni; v.z *= ni; v.w *= ni;
        *(float4*)&Wc[g][kk][i][0] = v;
    }
    #pragma unroll 5
    for (int idx = tid; idx < 1200; idx += 256) {
        int half = idx & 1, fr = idx >> 1;
        int i = fr % 25, kk = (fr / 25) % 3, g = fr / 75;
        int p0 = 2400 * g + 600 * u + 200 * kk + 8 * i + 4 * half;
        int h = p0 / 4800, r = p0 % 4800, t = r >> 6, f = r & 63;
        int row = (t < 56) ? t : t - 19;
        int tt = ib[h * 56 + row] % 56;
        *(float4*)&Vb[g][kk][i][4 * half] = *(const float4*)&q[tt * 96 + 32 + f];
    }
    // wbr: raw (unnormalized) w_b at kk==k for this thread's (g,i) -- direct gather
    const int g = tid & 7, i = tid >> 3;
    float4 wbr = {0.f, 0.f, 0.f, 0.f};
    if (tid < 200) {
        int p0 = 1200 * g + 300 * u + 100 * k + 4 * i;
        int h = p0 / 2400, r = p0 % 2400, t = r >> 5, f = r & 31;
        int row = (t < 56) ? t : t - 19;
        int tt = ib[h * 56 + row] % 56;
        wbr = *(const float4*)&q[tt * 96 + f];
    }
    __syncthreads();
    if (tid < 200) {
        float se = 0.f;
        float4 a0 = {0,0,0,0}, a1 = {0,0,0,0}, a2 = {0,0,0,0}, a3 = {0,0,0,0};
        #pragma unroll
        for (int ks = 0; ks < 3; ++ks) {
            #pragma unroll
            for (int jj = 0; jj < 25; ++jj) {
                const int tw = ks * 25 + jj;                  // static
                const int roww = (tw < 56) ? tw : tw - 19;    // static -> s_loads
                float4 we = *(const float4*)&rel[roww * 12];
                float rawv = dot4(wbr, *(const float4*)&Wc[g][ks][jj][0]);
                float embv = 0.1f * dot4(wbr, we);            // F_GW folded
                float p2 = rawv * rawv + embv * embv;
                p2 += __shfl_xor(p2, 1);                      // sum over 8 g-lanes
                p2 += __shfl_xor(p2, 2);
                p2 += __shfl_xor(p2, 4);
                float di = fminf(__builtin_amdgcn_rsqf(p2), INV_EPSN);
                float e = __builtin_amdgcn_exp2f((rawv + embv) * di * LOG2E);
                se += e;
                const float4* vv = (const float4*)&Vb[g][ks][jj][0];
                fma4(a0, e, vv[0]); fma4(a1, e, vv[1]);
                float4 ve0 = *(const float4*)&rel[roww * 12 + 4];
                float4 ve1 = *(const float4*)&rel[roww * 12 + 8];
                fma4(a2, e, ve0); fma4(a3, e, ve1);
            }
        }
        bsb[b * 2400 + g * 300 + u * 75 + k * 25 + i] =
            __builtin_amdgcn_logf(se) * LN2;                  // logsumexp, no shift
        const float rinv = 1.0f / se;
        const float r2 = 0.1f * rinv;            // F_GV1
        a0.x *= rinv; a0.y *= rinv; a0.z *= rinv; a0.w *= rinv;
        a1.x *= rinv; a1.y *= rinv; a1.z *= rinv; a1.w *= rinv;
        a2.x *= r2;   a2.y *= r2;   a2.z *= r2;   a2.w *= r2;
        a3.x *= r2;   a3.y *= r2;   a3.z *= r2;   a3.w *= r2;
        float* rp = Rb + b * 38400 + 4800 * g + 1200 * u + 400 * k + 16 * i;
        ((float4*)rp)[0] = a0;
        ((float4*)rp)[1] = a1;
        ((float4*)rp)[2] = a2;
        ((float4*)rp)[3] = a3;
    }
}

// ---------------- K45: channel l2norm + pair-sum + unsort + hash softmax
//                        + transposed FP32 store ----------------
__global__ __launch_bounds__(256) void k45_post(
        const float* __restrict__ Rb, const float* __restrict__ bsb,
        const int* __restrict__ idx_buf, float* __restrict__ out) {
    __shared__ float D[300];
    __shared__ float bsn[300];
    __shared__ float retU[224][64];
    __shared__ float bsU[224];
    __shared__ int idxL[224];
    const int b = blockIdx.x, tid = threadIdx.x;
    const int n = b / 56, w = b % 56;
    const float* R = Rb + b * 38400;
    if (tid < 224) idxL[tid] = idx_buf[b * 224 + tid];
    for (int r = tid; r < 300; r += 256) {
        float s = 0.f;
        #pragma unroll 16                        // 16 loads in flight (1 wave/SIMD!)
        for (int c = 0; c < 128; ++c) { float v = R[c * 300 + r]; s += v * v; }
        D[r] = fminf(__builtin_amdgcn_rsqf(s), INV_EPSN);   // reciprocal norm
    }
    for (int idx = tid; idx < 300; idx += 256) {
        int u = idx / 75, t = idx % 75;
        float s2 = 0.f, sum = 0.f;
        #pragma unroll
        for (int g = 0; g < 8; ++g) {
            float v = bsb[b * 2400 + g * 300 + u * 75 + t];
            s2 += v * v; sum += v;
        }
        bsn[idx] = sum / fmaxf(sqrtf(s2), EPSN);
    }
    __syncthreads();
    #pragma unroll 4
    for (int idx = tid; idx < 224 * 64; idx += 256) {
        int p = idx >> 6, o = idx & 63;
        int u3 = p / 56, t = p % 56;
        int k3 = t / 25, i3 = t % 25;
        int q0 = 9600 * u3 + 3200 * k3 + 128 * i3 + 2 * o;
        float2 rv = *(const float2*)&R[q0];
        int r0 = q0 % 300;                       // q0 even => r0+1 never wraps
        float val = rv.x * D[r0] + rv.y * D[r0 + 1];
        int r = idxL[p];
        retU[r][o] = val;
        if (o == 0) bsU[r] = bsn[u3 * 75 + t];
    }
    __syncthreads();
    for (int idx = tid; idx < 56 * 64; idx += 256) {
        int h = idx >> 6, o = idx & 63;
        float b0 = bsU[h], b1 = bsU[56 + h], b2 = bsU[112 + h], b3 = bsU[168 + h];
        float m = fmaxf(fmaxf(b0, b1), fmaxf(b2, b3));
        float e0 = __builtin_amdgcn_exp2f((b0 - m) * LOG2E);
        float e1 = __builtin_amdgcn_exp2f((b1 - m) * LOG2E);
        float e2 = __builtin_amdgcn_exp2f((b2 - m) * LOG2E);
        float e3 = __builtin_amdgcn_exp2f((b3 - m) * LOG2E);
        float ps = e0 + e1 + e2 + e3;
        float val = (retU[h][o] * e0 + retU[56 + h][o] * e1 +
                     retU[112 + h][o] * e2 + retU[168 + h][o] * e3) / ps;
        out[((n * 64 + o) * 56 + h) * 56 + w] = val;   // (n,o,h,w)
    }
}

extern "C" void kernel_launch(void* const* d_in, const int* in_sizes, int n_in,
                              void* d_out, int out_size, void* d_ws, size_t ws_size,
                              hipStream_t stream) {
    (void)in_sizes; (void)n_in; (void)out_size; (void)ws_size;
    const float* x     = (const float*)d_in[0];
    const float* cw    = (const float*)d_in[1];
    const float* gamma = (const float*)d_in[2];
    const float* beta  = (const float*)d_in[3];
    const float* rel   = (const float*)d_in[4];
    const float* rot   = (const float*)d_in[5];
    float* ws  = (float*)d_ws;
    float* qkv = ws;
    float* bsb = ws + 602112;
    float* Rb  = ws + 870912;
    int*   idx = (int*)(ws + 5171712);

    k12_qkv_sort<<<112, 256, 0, stream>>>(x, cw, gamma, beta, rot, qkv, idx);
    k3_attn<<<dim3(112, 4, 3), 256, 0, stream>>>(qkv, idx, rel, Rb, bsb);
    k45_post<<<112, 256, 0, stream>>>(Rb, bsb, idx, (float*)d_out);
}

// Round 3
// 154.458 us; speedup vs baseline: 1.1318x; 1.1274x over previous
//
#include <hip/hip_runtime.h>
#include <math.h>

// ============================================================================
// Sizes (fixed): N=2, C=64, Hax=56, W=56 -> B=112, H=56, OUT=64, N_HASHES=4,
// CHUNK=25, GROUPS=8, GP=8, hash_buckets=2, padding=19, K=3, qkv ch=96.
// Inputs fp32; OUTPUT FP32; stable argsort (established R8-R11).
// R15: fused single-pass, but launch_bounds(256,5) spilled (FETCH 17.6MB).
// R16: spill fixed (FETCH 1.5MB) but still 64.7us vs R14's 50.4 -> the
//      in-loop 3x shfl_xor norm chain (225 ds_swizzle/thread) is the cost.
// R17: DI back to a dedicated FMA-dense phase (R14-style) but TRANSPOSED
//      DIT[j][i] (kills R14's 407K bank conflicts); keep single-pass main
//      (no max pass, |ss|<=sqrt(2), validated R15/R16); idx gathers read
//      from LDS ibL (removes dependent global->global chains); k45 split
//      over (b, o-half) -> 224 blocks (was 112 = half the chip idle).
//
// ws layout (float slots):
//   qkv : [112][5376]   off 0
//   bsb : [112][2400]   off 602112
//   Rb  : [112][38400]  off 870912
//   idx : [112][224]    off 5171712  (int)
// ============================================================================

#define EPSN 5e-5f
#define INV_EPSN 20000.0f
#define LOG2E 1.4426950408889634f
#define LN2   0.6931471805599453f

__device__ __forceinline__ float dot4(const float4 a, const float4 b) {
    return a.x * b.x + a.y * b.y + a.z * b.z + a.w * b.w;
}
__device__ __forceinline__ void fma4(float4& a, float s, const float4 v) {
    a.x += s * v.x; a.y += s * v.y; a.z += s * v.z; a.w += s * v.w;
}

// ---------------- K12: qkv GEMM + BN + LSH codes + stable argsort ----------------
// o-quad register tile (4 outputs share one xv read); float4 LDS reads.
__global__ __launch_bounds__(256) void k12_qkv_sort(
        const float* __restrict__ x, const float* __restrict__ cw,
        const float* __restrict__ gamma, const float* __restrict__ beta,
        const float* __restrict__ rot, float* __restrict__ qkv,
        int* __restrict__ idx_buf) {
    __shared__ float xsT[56 * 68];   // [h][c], pad 64->68 (16B-aligned rows)
    __shared__ float cws[96 * 64];
    __shared__ float wm[56 * 32];    // w_match[t][f]
    __shared__ float rl[128];
    __shared__ float gs[96], bt[96];
    __shared__ int code[224];
    __shared__ int srt[224];
    const int b = blockIdx.x, n = b / 56, w = b % 56, tid = threadIdx.x;
    const float* xb = x + n * 200704 + w;
    #pragma unroll 7
    for (int i = tid; i < 3584; i += 256) {
        int c = i / 56, h = i % 56;
        xsT[h * 68 + c] = xb[c * 3136 + h * 56];
    }
    #pragma unroll 8
    for (int i = tid; i < 6144; i += 256) cws[i] = cw[i];
    if (tid < 128) rl[tid] = rot[tid];
    if (tid < 96) { gs[tid] = gamma[tid]; bt[tid] = beta[tid]; }
    __syncthreads();
    const float inv_s = 1.0f / sqrtf(1.0f + 1.0e-5f);
    // 1344 tiles = 24 o-quads x 56 h; each tile: 4 outputs, xv read once.
    for (int tl = tid; tl < 1344; tl += 256) {
        int oq = tl / 56, h = tl % 56;
        int o0 = oq * 4;
        float s0 = 0.f, s1 = 0.f, s2 = 0.f, s3 = 0.f;
        #pragma unroll
        for (int cs = 0; cs < 16; ++cs) {
            float4 xv = *(const float4*)&xsT[h * 68 + cs * 4];
            float4 c0 = *(const float4*)&cws[(o0 + 0) * 64 + cs * 4];
            float4 c1 = *(const float4*)&cws[(o0 + 1) * 64 + cs * 4];
            float4 c2 = *(const float4*)&cws[(o0 + 2) * 64 + cs * 4];
            float4 c3 = *(const float4*)&cws[(o0 + 3) * 64 + cs * 4];
            s0 += dot4(xv, c0); s1 += dot4(xv, c1);
            s2 += dot4(xv, c2); s3 += dot4(xv, c3);
        }
        #pragma unroll
        for (int qq = 0; qq < 4; ++qq) {
            int o = o0 + qq;
            float sv = (qq == 0) ? s0 : (qq == 1) ? s1 : (qq == 2) ? s2 : s3;
            float val = sv * inv_s * gs[o] + bt[o];
            int j = o * 56 + h;
            qkv[b * 5376 + j] = val;
            int f = j % 96;                      // raw (B,96,56)->(B,56,96) reshape
            if (f < 32) wm[(j / 96) * 32 + f] = val;
        }
    }
    __syncthreads();
    if (tid < 224) {
        int u = tid / 56, t = tid % 56;
        float s = 0.f;
        #pragma unroll 8
        for (int f = 0; f < 32; ++f) s += wm[t * 32 + f] * rl[f * 4 + u];
        code[tid] = ((s < 0.f) ? 1 : 0) + 2 * u; // argmax([s,-s]) + u*hash_buckets
    }
    __syncthreads();
    if (tid < 224) {
        int c = code[tid], r = 0;
        #pragma unroll 8
        for (int p = 0; p < 224; ++p) {
            int cp = code[p];
            r += (int)((cp < c) | ((cp == c) & (p < tid)));  // stable rank
        }
        srt[r] = tid;
    }
    __syncthreads();
    if (tid < 224) idx_buf[b * 224 + tid] = srt[tid];
}

// ---------------- K3: chunked attention, one block per (b,u,k) ----------------
// Phases: ibL stage -> gather/normalize -> DI phase (FMA-dense, DIT[j][i]) ->
// Wc += 0.1*we -> single-pass main (no max pass). LDS 40.4KB -> 4 blocks/CU.
__global__ __launch_bounds__(256) void k3_attn(
        const float* __restrict__ qkv, const int* __restrict__ idx_buf,
        const float* __restrict__ rel, float* __restrict__ Rb,
        float* __restrict__ bsb) {
    __shared__ __align__(16) float Wc[8][3][25][4];   // normalized, then +0.1*we
    __shared__ __align__(16) float Vb[8][3][25][8];
    __shared__ __align__(16) float WbK[8][25][4];     // raw w_b at kk==k
    __shared__ float DIT[75][25];                     // transposed inv-norm
    __shared__ int ibL[224];
    const int b = blockIdx.x, u = blockIdx.y, k = blockIdx.z;
    const int tid = threadIdx.x;
    const float* q = qkv + b * 5376;

    if (tid < 224) ibL[tid] = idx_buf[b * 224 + tid];
    __syncthreads();

    #pragma unroll 3
    for (int idx = tid; idx < 600; idx += 256) {
        int i = idx % 25, kk = (idx / 25) % 3, g = idx / 75;
        int p0 = 1200 * g + 300 * u + 100 * kk + 4 * i;
        int h = p0 / 2400, r = p0 % 2400, t = r >> 5, f = r & 31;
        int row = (t < 56) ? t : t - 19;
        int tt = ibL[h * 56 + row] % 56;
        float4 v = *(const float4*)&q[tt * 96 + f];
        if (kk == k) *(float4*)&WbK[g][i][0] = v;
        float ni = fminf(__builtin_amdgcn_rsqf(dot4(v, v)), INV_EPSN);
        v.x *= ni; v.y *= ni; v.z *= ni; v.w *= ni;
        *(float4*)&Wc[g][kk][i][0] = v;
    }
    #pragma unroll 5
    for (int idx = tid; idx < 1200; idx += 256) {
        int half = idx & 1, fr = idx >> 1;
        int i = fr % 25, kk = (fr / 25) % 3, g = fr / 75;
        int p0 = 2400 * g + 600 * u + 200 * kk + 8 * i + 4 * half;
        int h = p0 / 4800, r = p0 % 4800, t = r >> 6, f = r & 63;
        int row = (t < 56) ? t : t - 19;
        int tt = ibL[h * 56 + row] % 56;
        *(float4*)&Vb[g][kk][i][4 * half] = *(const float4*)&q[tt * 96 + 32 + f];
    }
    __syncthreads();

    // DI phase: 250 threads x 8 j's each; register wb8; writes DIT[j][i].
    if (tid < 250) {
        const int i = tid % 25, jg = tid / 25;
        float4 wb8[8];
        #pragma unroll
        for (int g = 0; g < 8; ++g) wb8[g] = *(const float4*)&WbK[g][i][0];
        #pragma unroll
        for (int it = 0; it < 8; ++it) {
            int j = jg * 8 + it;
            if (j < 75) {
                int ks = j / 25, jj = j % 25;
                int roww = (j < 56) ? j : j - 19;
                float4 we = *(const float4*)&rel[roww * 12];
                we.x *= 0.1f; we.y *= 0.1f; we.z *= 0.1f; we.w *= 0.1f;
                float s2 = 0.f;
                #pragma unroll
                for (int g = 0; g < 8; ++g) {
                    float4 wcn = *(const float4*)&Wc[g][ks][jj][0];
                    float raw = dot4(wb8[g], wcn);
                    float emb = dot4(wb8[g], we);
                    s2 += raw * raw + emb * emb;
                }
                DIT[j][i] = fminf(__builtin_amdgcn_rsqf(s2), INV_EPSN);
            }
        }
    }
    __syncthreads();

    // Fold 0.1*we into Wc so main loop is one dot4 per (g,j).
    #pragma unroll 3
    for (int idx = tid; idx < 600; idx += 256) {
        int i = idx % 25, kk = (idx / 25) % 3, g = idx / 75;
        int tw = kk * 25 + i;
        int roww = (tw < 56) ? tw : tw - 19;
        float4 we = *(const float4*)&rel[roww * 12];
        float4 v = *(const float4*)&Wc[g][kk][i][0];
        v.x += 0.1f * we.x; v.y += 0.1f * we.y;
        v.z += 0.1f * we.z; v.w += 0.1f * we.w;
        *(float4*)&Wc[g][kk][i][0] = v;
    }
    __syncthreads();

    if (tid < 200) {
        const int g = tid & 7, i = tid >> 3;
        const float4 wbr = *(const float4*)&WbK[g][i][0];
        float se = 0.f;
        float4 a0 = {0,0,0,0}, a1 = {0,0,0,0}, a2 = {0,0,0,0}, a3 = {0,0,0,0};
        #pragma unroll
        for (int ks = 0; ks < 3; ++ks) {
            #pragma unroll
            for (int jj = 0; jj < 25; ++jj) {
                const int jP = ks * 25 + jj;                  // static
                const int roww = (jP < 56) ? jP : jP - 19;    // static -> s_loads
                float di = DIT[jP][i];
                float e = __builtin_amdgcn_exp2f(
                    dot4(wbr, *(const float4*)&Wc[g][ks][jj][0]) * di * LOG2E);
                se += e;
                const float4* vv = (const float4*)&Vb[g][ks][jj][0];
                fma4(a0, e, vv[0]); fma4(a1, e, vv[1]);
                float4 ve0 = *(const float4*)&rel[roww * 12 + 4];
                float4 ve1 = *(const float4*)&rel[roww * 12 + 8];
                fma4(a2, e, ve0); fma4(a3, e, ve1);
            }
        }
        bsb[b * 2400 + g * 300 + u * 75 + k * 25 + i] =
            __builtin_amdgcn_logf(se) * LN2;                  // logsumexp, no shift
        const float rinv = 1.0f / se;
        const float r2 = 0.1f * rinv;            // F_GV1
        a0.x *= rinv; a0.y *= rinv; a0.z *= rinv; a0.w *= rinv;
        a1.x *= rinv; a1.y *= rinv; a1.z *= rinv; a1.w *= rinv;
        a2.x *= r2;   a2.y *= r2;   a2.z *= r2;   a2.w *= r2;
        a3.x *= r2;   a3.y *= r2;   a3.z *= r2;   a3.w *= r2;
        float* rp = Rb + b * 38400 + 4800 * g + 1200 * u + 400 * k + 16 * i;
        ((float4*)rp)[0] = a0;
        ((float4*)rp)[1] = a1;
        ((float4*)rp)[2] = a2;
        ((float4*)rp)[3] = a3;
    }
}

// ---------------- K45: channel l2norm + pair-sum + unsort + hash softmax
//                        + transposed FP32 store. Split over (b, o-half). ----------------
__global__ __launch_bounds__(256) void k45_post(
        const float* __restrict__ Rb, const float* __restrict__ bsb,
        const int* __restrict__ idx_buf, float* __restrict__ out) {
    __shared__ float D[300];
    __shared__ float bsn[300];
    __shared__ float retU[224][32];
    __shared__ float bsU[224];
    __shared__ int idxL[224];
    const int b = blockIdx.x, oh = blockIdx.y, tid = threadIdx.x;
    const int n = b / 56, w = b % 56, o0 = oh * 32;
    const float* R = Rb + b * 38400;
    if (tid < 224) idxL[tid] = idx_buf[b * 224 + tid];
    for (int r = tid; r < 300; r += 256) {
        float s = 0.f;
        #pragma unroll 16                        // keep 16 loads in flight
        for (int c = 0; c < 128; ++c) { float v = R[c * 300 + r]; s += v * v; }
        D[r] = fminf(__builtin_amdgcn_rsqf(s), INV_EPSN);   // reciprocal norm
    }
    for (int idx = tid; idx < 300; idx += 256) {
        int u = idx / 75, t = idx % 75;
        float s2 = 0.f, sum = 0.f;
        #pragma unroll
        for (int g = 0; g < 8; ++g) {
            float v = bsb[b * 2400 + g * 300 + u * 75 + t];
            s2 += v * v; sum += v;
        }
        bsn[idx] = sum / fmaxf(sqrtf(s2), EPSN);
    }
    __syncthreads();
    if (tid < 224) {
        int u3 = tid / 56, t = tid % 56;
        bsU[idxL[tid]] = bsn[u3 * 75 + t];
    }
    #pragma unroll 4
    for (int idx = tid; idx < 224 * 32; idx += 256) {
        int p = idx >> 5, oc = idx & 31;
        int o = o0 + oc;
        int u3 = p / 56, t = p % 56;
        int k3 = t / 25, i3 = t % 25;
        int q0 = 9600 * u3 + 3200 * k3 + 128 * i3 + 2 * o;
        float2 rv = *(const float2*)&R[q0];
        int r0 = q0 % 300;                       // q0 even => r0+1 never wraps
        float val = rv.x * D[r0] + rv.y * D[r0 + 1];
        retU[idxL[p]][oc] = val;
    }
    __syncthreads();
    for (int idx = tid; idx < 56 * 32; idx += 256) {
        int h = idx >> 5, oc = idx & 31;
        int o = o0 + oc;
        float b0 = bsU[h], b1 = bsU[56 + h], b2 = bsU[112 + h], b3 = bsU[168 + h];
        float m = fmaxf(fmaxf(b0, b1), fmaxf(b2, b3));
        float e0 = __builtin_amdgcn_exp2f((b0 - m) * LOG2E);
        float e1 = __builtin_amdgcn_exp2f((b1 - m) * LOG2E);
        float e2 = __builtin_amdgcn_exp2f((b2 - m) * LOG2E);
        float e3 = __builtin_amdgcn_exp2f((b3 - m) * LOG2E);
        float ps = e0 + e1 + e2 + e3;
        float val = (retU[h][oc] * e0 + retU[56 + h][oc] * e1 +
                     retU[112 + h][oc] * e2 + retU[168 + h][oc] * e3) / ps;
        out[((n * 64 + o) * 56 + h) * 56 + w] = val;   // (n,o,h,w)
    }
}

extern "C" void kernel_launch(void* const* d_in, const int* in_sizes, int n_in,
                              void* d_out, int out_size, void* d_ws, size_t ws_size,
                              hipStream_t stream) {
    (void)in_sizes; (void)n_in; (void)out_size; (void)ws_size;
    const float* x     = (const float*)d_in[0];
    const float* cw    = (const float*)d_in[1];
    const float* gamma = (const float*)d_in[2];
    const float* beta  = (const float*)d_in[3];
    const float* rel   = (const float*)d_in[4];
    const float* rot   = (const float*)d_in[5];
    float* ws  = (float*)d_ws;
    float* qkv = ws;
    float* bsb = ws + 602112;
    float* Rb  = ws + 870912;
    int*   idx = (int*)(ws + 5171712);

    k12_qkv_sort<<<112, 256, 0, stream>>>(x, cw, gamma, beta, rot, qkv, idx);
    k3_attn<<<dim3(112, 4, 3), 256, 0, stream>>>(qkv, idx, rel, Rb, bsb);
    k45_post<<<dim3(112, 2), 256, 0, stream>>>(Rb, bsb, idx, (float*)d_out);
}